// Round 4
// baseline (6612.471 us; speedup 1.0000x reference)
//
#include <hip/hip_runtime.h>

// Problem constants (DeepCAD_1958505087412)
#define BB   8
#define NN   512      // nodes == timesteps
#define NDIM 128
#define HDIM 256      // GNN out dim == LSTM hidden
#define TT   512

__device__ __forceinline__ float sigmoidf_(float x) { return 1.0f / (1.0f + __expf(-x)); }
__device__ __forceinline__ float tanhf_(float x) { float e = __expf(2.0f * x); return 1.0f - 2.0f / (e + 1.0f); }

// ---------------------------------------------------------------------------
// Y = X @ W^T + bias (optional ReLU). X:(M,K) W:(Nn,K) Y:(M,Nn) row-major.
// 64x64 tile, BK=16, 256 threads, 4x4 per thread. M%64==0, K%16==0 assumed.
// ---------------------------------------------------------------------------
template<int RELU>
__global__ __launch_bounds__(256) void gemm_nt(const float* __restrict__ X,
    const float* __restrict__ W, const float* __restrict__ bias,
    float* __restrict__ Y, int M, int K, int Nn)
{
    __shared__ float Xs[16][68];
    __shared__ float Ws[16][68];
    const int tid = threadIdx.x;
    const int m0 = blockIdx.y << 6;
    const int n0 = blockIdx.x << 6;
    const int lr = tid >> 2;           // 0..63
    const int lc = (tid & 3) << 2;     // 0,4,8,12
    const int tm = (tid >> 4) << 2;    // 0..60
    const int tn = (tid & 15) << 2;    // 0..60

    float acc[4][4] = {{0.f,0.f,0.f,0.f},{0.f,0.f,0.f,0.f},{0.f,0.f,0.f,0.f},{0.f,0.f,0.f,0.f}};

    const float* Xp = X + (size_t)(m0 + lr) * K + lc;
    const bool wok = (n0 + lr) < Nn;
    const float* Wp = wok ? (W + (size_t)(n0 + lr) * K + lc) : W;

    for (int k0 = 0; k0 < K; k0 += 16) {
        float4 xv = *(const float4*)(Xp + k0);
        float4 wv = *(const float4*)(Wp + k0);
        if (!wok) wv = make_float4(0.f, 0.f, 0.f, 0.f);
        __syncthreads();
        Xs[lc+0][lr]=xv.x; Xs[lc+1][lr]=xv.y; Xs[lc+2][lr]=xv.z; Xs[lc+3][lr]=xv.w;
        Ws[lc+0][lr]=wv.x; Ws[lc+1][lr]=wv.y; Ws[lc+2][lr]=wv.z; Ws[lc+3][lr]=wv.w;
        __syncthreads();
        #pragma unroll
        for (int kk = 0; kk < 16; ++kk) {
            const float4 a = *(const float4*)(&Xs[kk][tm]);
            const float4 b = *(const float4*)(&Ws[kk][tn]);
            acc[0][0] += a.x*b.x; acc[0][1] += a.x*b.y; acc[0][2] += a.x*b.z; acc[0][3] += a.x*b.w;
            acc[1][0] += a.y*b.x; acc[1][1] += a.y*b.y; acc[1][2] += a.y*b.z; acc[1][3] += a.y*b.w;
            acc[2][0] += a.z*b.x; acc[2][1] += a.z*b.y; acc[2][2] += a.z*b.z; acc[2][3] += a.z*b.w;
            acc[3][0] += a.w*b.x; acc[3][1] += a.w*b.y; acc[3][2] += a.w*b.z; acc[3][3] += a.w*b.w;
        }
    }
    const int nc = n0 + tn;
    if (nc >= Nn) return;
    float4 bv = make_float4(0.f, 0.f, 0.f, 0.f);
    if (bias) bv = *(const float4*)(bias + nc);
    #pragma unroll
    for (int i = 0; i < 4; ++i) {
        float4 o;
        o.x = acc[i][0] + bv.x; o.y = acc[i][1] + bv.y;
        o.z = acc[i][2] + bv.z; o.w = acc[i][3] + bv.w;
        if (RELU) { o.x=fmaxf(o.x,0.f); o.y=fmaxf(o.y,0.f); o.z=fmaxf(o.z,0.f); o.w=fmaxf(o.w,0.f); }
        *(float4*)(Y + (size_t)(m0 + tm + i) * Nn + nc) = o;
    }
}

// ---------------------------------------------------------------------------
// Batched Y[b] = (A[b] @ H[b]) * mask[b,:,None], optional ReLU.
// ---------------------------------------------------------------------------
template<int RELU>
__global__ __launch_bounds__(256) void gemm_nn_mask(const float* __restrict__ A,
    const float* __restrict__ Hm, const float* __restrict__ mask,
    float* __restrict__ Y, int M, int K, int Nn)
{
    const int b = blockIdx.z;
    A  += (size_t)b * M * K;
    Hm += (size_t)b * K * Nn;
    Y  += (size_t)b * M * Nn;
    __shared__ float As[16][68];
    __shared__ float Hs[16][68];
    const int tid = threadIdx.x;
    const int m0 = blockIdx.y << 6;
    const int n0 = blockIdx.x << 6;
    const int lr = tid >> 2;
    const int lc = (tid & 3) << 2;
    const int hr = tid >> 4;           // 0..15
    const int hc = (tid & 15) << 2;    // 0..60
    const int tm = (tid >> 4) << 2;
    const int tn = (tid & 15) << 2;

    float acc[4][4] = {{0.f,0.f,0.f,0.f},{0.f,0.f,0.f,0.f},{0.f,0.f,0.f,0.f},{0.f,0.f,0.f,0.f}};

    for (int k0 = 0; k0 < K; k0 += 16) {
        float4 av = *(const float4*)(A + (size_t)(m0 + lr) * K + k0 + lc);
        float4 hv = *(const float4*)(Hm + (size_t)(k0 + hr) * Nn + n0 + hc);
        __syncthreads();
        As[lc+0][lr]=av.x; As[lc+1][lr]=av.y; As[lc+2][lr]=av.z; As[lc+3][lr]=av.w;
        *(float4*)(&Hs[hr][hc]) = hv;
        __syncthreads();
        #pragma unroll
        for (int kk = 0; kk < 16; ++kk) {
            const float4 a = *(const float4*)(&As[kk][tm]);
            const float4 h = *(const float4*)(&Hs[kk][tn]);
            acc[0][0] += a.x*h.x; acc[0][1] += a.x*h.y; acc[0][2] += a.x*h.z; acc[0][3] += a.x*h.w;
            acc[1][0] += a.y*h.x; acc[1][1] += a.y*h.y; acc[1][2] += a.y*h.z; acc[1][3] += a.y*h.w;
            acc[2][0] += a.z*h.x; acc[2][1] += a.z*h.y; acc[2][2] += a.z*h.z; acc[2][3] += a.z*h.w;
            acc[3][0] += a.w*h.x; acc[3][1] += a.w*h.y; acc[3][2] += a.w*h.z; acc[3][3] += a.w*h.w;
        }
    }
    #pragma unroll
    for (int i = 0; i < 4; ++i) {
        const float mk = mask[b * M + m0 + tm + i];
        float4 o;
        o.x = acc[i][0]*mk; o.y = acc[i][1]*mk; o.z = acc[i][2]*mk; o.w = acc[i][3]*mk;
        if (RELU) { o.x=fmaxf(o.x,0.f); o.y=fmaxf(o.y,0.f); o.z=fmaxf(o.z,0.f); o.w=fmaxf(o.w,0.f); }
        *(float4*)(Y + (size_t)(m0 + tm + i) * Nn + n0 + tn) = o;
    }
}

// ---------------------------------------------------------------------------
__global__ __launch_bounds__(256) void attn_sisj(const float* __restrict__ h,
    const float* __restrict__ aw, const float* __restrict__ ab,
    float* __restrict__ si, float* __restrict__ sj)
{
    const int lane = threadIdx.x & 63;
    const int row  = (blockIdx.x << 2) + (threadIdx.x >> 6);
    const float4 hv = ((const float4*)(h + (size_t)row * HDIM))[lane];
    const float4 a1 = ((const float4*)aw)[lane];
    const float4 a2 = ((const float4*)(aw + HDIM))[lane];
    float s1 = hv.x*a1.x + hv.y*a1.y + hv.z*a1.z + hv.w*a1.w;
    float s2 = hv.x*a2.x + hv.y*a2.y + hv.z*a2.z + hv.w*a2.w;
    #pragma unroll
    for (int off = 32; off > 0; off >>= 1) {
        s1 += __shfl_down(s1, off);
        s2 += __shfl_down(s2, off);
    }
    if (lane == 0) { si[row] = s1 + ab[0]; sj[row] = s2; }
}

// ---------------------------------------------------------------------------
__global__ __launch_bounds__(512) void attn_score(const float* __restrict__ si,
    const float* __restrict__ sj, const float* __restrict__ adj,
    const float* __restrict__ mask, float* __restrict__ watt)
{
    const int bi = blockIdx.x;           // b*NN + i
    const int b  = bi >> 9;
    const int j  = threadIdx.x;
    const float s0 = si[bi];
    const float mi = mask[bi];
    float s = sigmoidf_(s0 + sj[(b << 9) + j]) * adj[(size_t)bi * NN + j] * mi * mask[(b << 9) + j];
    float t = s;
    #pragma unroll
    for (int off = 32; off > 0; off >>= 1) t += __shfl_down(t, off);
    __shared__ float red[8];
    const int lane = j & 63, wv = j >> 6;
    if (lane == 0) red[wv] = t;
    __syncthreads();
    if (j == 0) {
        float tot = 0.f;
        #pragma unroll
        for (int w = 0; w < 8; ++w) tot += red[w];
        red[0] = 1.0f / (tot + 1e-8f);
    }
    __syncthreads();
    watt[(size_t)bi * NN + j] = s * red[0];
}

// ---------------------------------------------------------------------------
__global__ __launch_bounds__(256) void zero_ws(float* __restrict__ p, int n)
{
    for (int i = threadIdx.x + blockIdx.x * 256; i < n; i += 256 * gridDim.x) p[i] = 0.f;
}

// ---------------------------------------------------------------------------
// Cooperative multi-block LSTM scan, register-stationary weights.
// Grid: 256 blocks = 16 chains x 16 slices; blockIdx = slice*16 + chain so all
// slices of a chain land on one XCD (round-robin heuristic; correctness never
// depends on it). Block: 256 threads. Each block owns 16 hidden units
// (=64 gate rows); thread (row=t0>>2, kq=t0&3) dots k = kq*4+16*q'+e, holding
// its 64 weights in 16 NAMED float4 registers (no alloca -> no scratch).
// Per-step h exchange through a double-buffered global buffer + per-slice
// monotonic flags (agent-scope atomics).
//   hb: float[2][16][256] (zeroed)   fl: int[16][16] (zeroed)
// ---------------------------------------------------------------------------
__global__ __launch_bounds__(256, 1) void lstm_scan3(const float* __restrict__ pre_f,
    const float* __restrict__ pre_b, const float* __restrict__ whh_f,
    const float* __restrict__ whh_b, float* __restrict__ out,
    float* __restrict__ hb, int* __restrict__ fl)
{
    const int chain = blockIdx.x & 15;   // 0..15
    const int slice = blockIdx.x >> 4;   // 0..15
    const int batch = chain >> 1;
    const int dir   = chain & 1;
    const float* pre = dir ? pre_b : pre_f;
    const float* whh = dir ? whh_b : whh_f;

    const int t0   = threadIdx.x;
    const int row  = t0 >> 2;            // 0..63 local gate row
    const int kq   = t0 & 3;             // K-quarter interleave phase
    const int gate = row >> 4;           // 0..3 = i,f,g,o
    const int j    = row & 15;           // hidden unit within slice
    const int grow = gate * 256 + slice * 16 + j;   // row in whh (1024x256)

    // ---- weights -> 16 named float4 registers (one-time) ----
    const float4* wrow4 = (const float4*)(whh + (size_t)grow * 256);
#define WDECL(i) const float4 W##i = wrow4[kq + 4 * i];
    WDECL(0) WDECL(1) WDECL(2) WDECL(3) WDECL(4) WDECL(5) WDECL(6) WDECL(7)
    WDECL(8) WDECL(9) WDECL(10) WDECL(11) WDECL(12) WDECL(13) WDECL(14) WDECL(15)
#undef WDECL

    __shared__ float4 h_s4[64];
    __shared__ float g_s[64];
    float c = 0.f;
    int* myflags = fl + chain * 16;
    float* hb_chain = hb + chain * 256;

    // prefetch pre for t=0
    const int tt0 = dir ? (TT - 1) : 0;
    float pv = pre[((size_t)batch * TT + tt0) * 1024 + grow];

    for (int t = 0; t < TT; ++t) {
        const int tt = dir ? (TT - 1 - t) : t;

        // ---- wait until all 16 slices of this chain published h_t ----
        if (t > 0) {
            if (t0 < 16) {
                while (__hip_atomic_load(&myflags[t0], __ATOMIC_ACQUIRE,
                                         __HIP_MEMORY_SCOPE_AGENT) < t) { }
            }
            __syncthreads();
        }

        // ---- read h_t (coherent double buffer), 1 float/thread ----
        ((float*)h_s4)[t0] = __hip_atomic_load(&hb_chain[(size_t)(t & 1) * 4096 + t0],
                                               __ATOMIC_RELAXED, __HIP_MEMORY_SCOPE_AGENT);

        // ---- prefetch next step's pre value (hides HBM latency) ----
        float pv_next = 0.f;
        if (t + 1 < TT) {
            const int ttn = dir ? (TT - 2 - t) : (t + 1);
            pv_next = pre[((size_t)batch * TT + ttn) * 1024 + grow];
        }
        __syncthreads();

        // ---- matvec: 16 conflict-free ds_read_b128 + 64 FMAs ----
        float g = 0.f;
        {
            const float4* h4 = (const float4*)h_s4;
#define WDOT(i) { const float4 hv = h4[kq + 4 * i]; \
                  g += W##i.x * hv.x + W##i.y * hv.y + W##i.z * hv.z + W##i.w * hv.w; }
            WDOT(0) WDOT(1) WDOT(2) WDOT(3) WDOT(4) WDOT(5) WDOT(6) WDOT(7)
            WDOT(8) WDOT(9) WDOT(10) WDOT(11) WDOT(12) WDOT(13) WDOT(14) WDOT(15)
#undef WDOT
        }
        g += __shfl_xor(g, 1);
        g += __shfl_xor(g, 2);
        if (kq == 0) g_s[row] = g + pv;
        __syncthreads();

        // ---- pointwise update for this block's 16 hidden units ----
        if (t0 < 16) {
            const float ig = sigmoidf_(g_s[t0]);
            const float fg = sigmoidf_(g_s[16 + t0]);
            const float gg = tanhf_(g_s[32 + t0]);
            const float og = sigmoidf_(g_s[48 + t0]);
            c = fg * c + ig * gg;
            const float hnew = og * tanhf_(c);
            const int hcol = slice * 16 + t0;
            __hip_atomic_store(&hb_chain[(size_t)((t + 1) & 1) * 4096 + hcol], hnew,
                               __ATOMIC_RELAXED, __HIP_MEMORY_SCOPE_AGENT);
            out[((size_t)batch * TT + tt) * 512 + dir * 256 + hcol] = hnew;
        }
        __syncthreads();                 // drains vmcnt: h stores device-visible

        if (t0 == 0)
            __hip_atomic_store(&myflags[slice], t + 1, __ATOMIC_RELEASE,
                               __HIP_MEMORY_SCOPE_AGENT);
        pv = pv_next;
    }
}

// ---------------------------------------------------------------------------

extern "C" void kernel_launch(void* const* d_in, const int* in_sizes, int n_in,
                              void* d_out, int out_size, void* d_ws, size_t ws_size,
                              hipStream_t stream)
{
    const float* nf   = (const float*)d_in[0];
    const float* adj  = (const float*)d_in[1];
    const float* mask = (const float*)d_in[2];
    const float* g_w[3]  = {(const float*)d_in[4],  (const float*)d_in[8],  (const float*)d_in[12]};
    const float* g_b[3]  = {(const float*)d_in[5],  (const float*)d_in[9],  (const float*)d_in[13]};
    const float* g_aw[3] = {(const float*)d_in[6],  (const float*)d_in[10], (const float*)d_in[14]};
    const float* g_ab[3] = {(const float*)d_in[7],  (const float*)d_in[11], (const float*)d_in[15]};
    const float* wih0f = (const float*)d_in[16]; const float* whh0f = (const float*)d_in[17]; const float* b0f = (const float*)d_in[18];
    const float* wih0b = (const float*)d_in[19]; const float* whh0b = (const float*)d_in[20]; const float* b0b = (const float*)d_in[21];
    const float* wih1f = (const float*)d_in[22]; const float* whh1f = (const float*)d_in[23]; const float* b1f = (const float*)d_in[24];
    const float* wih1b = (const float*)d_in[25]; const float* whh1b = (const float*)d_in[26]; const float* b1b = (const float*)d_in[27];

    float* ws = (float*)d_ws;
    // Workspace layout (floats); total ~15.7M floats = ~63 MB
    float* bufA = ws;                       // (4096,256)  GNN h projection / head tmp / sync scratch
    float* bufB = bufA + 1048576;           // (4096,256)  GNN layer output
    float* bufC = bufB + 1048576;           // (4096,256)  GNN3 output (kept for nd head)
    float* si   = bufC + 1048576;           // (4096)
    float* sj   = si + 4096;                // (4096)
    float* out0 = sj + 4096;                // (4096,512) LSTM layer0 output
    float* out1 = out0 + 2097152;           // (4096,512) LSTM layer1 output
    float* P0   = out1 + 2097152;           // (4096,1024) pre-activations fwd
    float* P1   = P0 + 4194304;             // (4096,1024) pre-activations bwd
    float* watt = P0;                       // alias: attention weights (GNN phase only)
    // scan sync state aliased onto bufA (free during the LSTM phase):
    float* hb = bufA;                       // [2][16][256] = 8192 floats
    int*   fl = (int*)(bufA + 8192);        // [16][16] = 256 ints
    const int SYNC_FLOATS = 8192 + 256;

    const int MR = BB * NN;                 // 4096 rows
    dim3 blk(256);

    // ---------------- GNN x3 ----------------
    auto run_gnn = [&](const float* xin, int Kin, int li, float* ob, bool relu) {
        gemm_nt<0><<<dim3(HDIM / 64, MR / 64), blk, 0, stream>>>(xin, g_w[li], g_b[li], bufA, MR, Kin, HDIM);
        attn_sisj<<<dim3(MR / 4), blk, 0, stream>>>(bufA, g_aw[li], g_ab[li], si, sj);
        attn_score<<<dim3(MR), dim3(512), 0, stream>>>(si, sj, adj, mask, watt);
        if (relu)
            gemm_nn_mask<1><<<dim3(HDIM / 64, NN / 64, BB), blk, 0, stream>>>(watt, bufA, mask, ob, NN, NN, HDIM);
        else
            gemm_nn_mask<0><<<dim3(HDIM / 64, NN / 64, BB), blk, 0, stream>>>(watt, bufA, mask, ob, NN, NN, HDIM);
    };
    run_gnn(nf,   NDIM, 0, bufB, true);
    run_gnn(bufB, HDIM, 1, bufB, true);
    run_gnn(bufB, HDIM, 2, bufC, false);

    // ---------------- LSTM layer 0 ----------------
    gemm_nt<0><<<dim3(16, MR / 64), blk, 0, stream>>>(bufC, wih0f, b0f, P0, MR, HDIM, 1024);
    gemm_nt<0><<<dim3(16, MR / 64), blk, 0, stream>>>(bufC, wih0b, b0b, P1, MR, HDIM, 1024);
    zero_ws<<<dim3(8), blk, 0, stream>>>(bufA, SYNC_FLOATS);
    lstm_scan3<<<dim3(256), blk, 0, stream>>>(P0, P1, whh0f, whh0b, out0, hb, fl);

    // ---------------- LSTM layer 1 ----------------
    gemm_nt<0><<<dim3(16, MR / 64), blk, 0, stream>>>(out0, wih1f, b1f, P0, MR, 512, 1024);
    gemm_nt<0><<<dim3(16, MR / 64), blk, 0, stream>>>(out0, wih1b, b1b, P1, MR, 512, 1024);
    zero_ws<<<dim3(8), blk, 0, stream>>>(bufA, SYNC_FLOATS);
    lstm_scan3<<<dim3(256), blk, 0, stream>>>(P0, P1, whh1f, whh1b, out1, hb, fl);

    // ---------------- Heads ----------------
    float* out = (float*)d_out;
    // op: (B,N,64) at offset 0
    gemm_nt<1><<<dim3(4, MR / 64), blk, 0, stream>>>(out1, (const float*)d_in[28], (const float*)d_in[29], bufA, MR, 512, 256);
    gemm_nt<0><<<dim3(1, MR / 64), blk, 0, stream>>>(bufA, (const float*)d_in[30], (const float*)d_in[31], out, MR, 256, 64);
    // pp: (B,N,16) at offset 262144
    gemm_nt<1><<<dim3(4, MR / 64), blk, 0, stream>>>(out1, (const float*)d_in[32], (const float*)d_in[33], bufA, MR, 512, 256);
    gemm_nt<0><<<dim3(1, MR / 64), blk, 0, stream>>>(bufA, (const float*)d_in[34], (const float*)d_in[35], out + 262144, MR, 256, 16);
    // sk: (B,N,128) at offset 327680
    gemm_nt<1><<<dim3(4, MR / 64), blk, 0, stream>>>(out1, (const float*)d_in[36], (const float*)d_in[37], bufA, MR, 512, 256);
    gemm_nt<0><<<dim3(2, MR / 64), blk, 0, stream>>>(bufA, (const float*)d_in[38], (const float*)d_in[39], out + 327680, MR, 256, 128);
    // nd: (B,N,128) at offset 851968 (input = GNN3 output)
    gemm_nt<1><<<dim3(4, MR / 64), blk, 0, stream>>>(bufC, (const float*)d_in[40], (const float*)d_in[41], bufA, MR, 256, 256);
    gemm_nt<0><<<dim3(2, MR / 64), blk, 0, stream>>>(bufA, (const float*)d_in[42], (const float*)d_in[43], out + 851968, MR, 256, 128);
}

// Round 5
// 4550.407 us; speedup vs baseline: 1.4532x; 1.4532x over previous
//
#include <hip/hip_runtime.h>

// Problem constants (DeepCAD_1958505087412)
#define BB   8
#define NN   512      // nodes == timesteps
#define NDIM 128
#define HDIM 256      // GNN out dim == LSTM hidden
#define TT   512

__device__ __forceinline__ float sigmoidf_(float x) { return 1.0f / (1.0f + __expf(-x)); }
__device__ __forceinline__ float tanhf_(float x) { float e = __expf(2.0f * x); return 1.0f - 2.0f / (e + 1.0f); }

typedef _Float16 half2v __attribute__((ext_vector_type(2)));
__device__ __forceinline__ float fdot2_(unsigned int w, unsigned int h, float acc) {
    return __builtin_amdgcn_fdot2(__builtin_bit_cast(half2v, w),
                                  __builtin_bit_cast(half2v, h), acc, false);
}

// ---------------------------------------------------------------------------
// Y = X @ W^T + bias (optional ReLU). X:(M,K) W:(Nn,K) Y:(M,Nn) row-major.
// ---------------------------------------------------------------------------
template<int RELU>
__global__ __launch_bounds__(256) void gemm_nt(const float* __restrict__ X,
    const float* __restrict__ W, const float* __restrict__ bias,
    float* __restrict__ Y, int M, int K, int Nn)
{
    __shared__ float Xs[16][68];
    __shared__ float Ws[16][68];
    const int tid = threadIdx.x;
    const int m0 = blockIdx.y << 6;
    const int n0 = blockIdx.x << 6;
    const int lr = tid >> 2;           // 0..63
    const int lc = (tid & 3) << 2;     // 0,4,8,12
    const int tm = (tid >> 4) << 2;    // 0..60
    const int tn = (tid & 15) << 2;    // 0..60

    float acc[4][4] = {{0.f,0.f,0.f,0.f},{0.f,0.f,0.f,0.f},{0.f,0.f,0.f,0.f},{0.f,0.f,0.f,0.f}};

    const float* Xp = X + (size_t)(m0 + lr) * K + lc;
    const bool wok = (n0 + lr) < Nn;
    const float* Wp = wok ? (W + (size_t)(n0 + lr) * K + lc) : W;

    for (int k0 = 0; k0 < K; k0 += 16) {
        float4 xv = *(const float4*)(Xp + k0);
        float4 wv = *(const float4*)(Wp + k0);
        if (!wok) wv = make_float4(0.f, 0.f, 0.f, 0.f);
        __syncthreads();
        Xs[lc+0][lr]=xv.x; Xs[lc+1][lr]=xv.y; Xs[lc+2][lr]=xv.z; Xs[lc+3][lr]=xv.w;
        Ws[lc+0][lr]=wv.x; Ws[lc+1][lr]=wv.y; Ws[lc+2][lr]=wv.z; Ws[lc+3][lr]=wv.w;
        __syncthreads();
        #pragma unroll
        for (int kk = 0; kk < 16; ++kk) {
            const float4 a = *(const float4*)(&Xs[kk][tm]);
            const float4 b = *(const float4*)(&Ws[kk][tn]);
            acc[0][0] += a.x*b.x; acc[0][1] += a.x*b.y; acc[0][2] += a.x*b.z; acc[0][3] += a.x*b.w;
            acc[1][0] += a.y*b.x; acc[1][1] += a.y*b.y; acc[1][2] += a.y*b.z; acc[1][3] += a.y*b.w;
            acc[2][0] += a.z*b.x; acc[2][1] += a.z*b.y; acc[2][2] += a.z*b.z; acc[2][3] += a.z*b.w;
            acc[3][0] += a.w*b.x; acc[3][1] += a.w*b.y; acc[3][2] += a.w*b.z; acc[3][3] += a.w*b.w;
        }
    }
    const int nc = n0 + tn;
    if (nc >= Nn) return;
    float4 bv = make_float4(0.f, 0.f, 0.f, 0.f);
    if (bias) bv = *(const float4*)(bias + nc);
    #pragma unroll
    for (int i = 0; i < 4; ++i) {
        float4 o;
        o.x = acc[i][0] + bv.x; o.y = acc[i][1] + bv.y;
        o.z = acc[i][2] + bv.z; o.w = acc[i][3] + bv.w;
        if (RELU) { o.x=fmaxf(o.x,0.f); o.y=fmaxf(o.y,0.f); o.z=fmaxf(o.z,0.f); o.w=fmaxf(o.w,0.f); }
        *(float4*)(Y + (size_t)(m0 + tm + i) * Nn + nc) = o;
    }
}

// ---------------------------------------------------------------------------
// Batched Y[b] = (A[b] @ H[b]) * mask[b,:,None], optional ReLU.
// ---------------------------------------------------------------------------
template<int RELU>
__global__ __launch_bounds__(256) void gemm_nn_mask(const float* __restrict__ A,
    const float* __restrict__ Hm, const float* __restrict__ mask,
    float* __restrict__ Y, int M, int K, int Nn)
{
    const int b = blockIdx.z;
    A  += (size_t)b * M * K;
    Hm += (size_t)b * K * Nn;
    Y  += (size_t)b * M * Nn;
    __shared__ float As[16][68];
    __shared__ float Hs[16][68];
    const int tid = threadIdx.x;
    const int m0 = blockIdx.y << 6;
    const int n0 = blockIdx.x << 6;
    const int lr = tid >> 2;
    const int lc = (tid & 3) << 2;
    const int hr = tid >> 4;           // 0..15
    const int hc = (tid & 15) << 2;    // 0..60
    const int tm = (tid >> 4) << 2;
    const int tn = (tid & 15) << 2;

    float acc[4][4] = {{0.f,0.f,0.f,0.f},{0.f,0.f,0.f,0.f},{0.f,0.f,0.f,0.f},{0.f,0.f,0.f,0.f}};

    for (int k0 = 0; k0 < K; k0 += 16) {
        float4 av = *(const float4*)(A + (size_t)(m0 + lr) * K + k0 + lc);
        float4 hv = *(const float4*)(Hm + (size_t)(k0 + hr) * Nn + n0 + hc);
        __syncthreads();
        As[lc+0][lr]=av.x; As[lc+1][lr]=av.y; As[lc+2][lr]=av.z; As[lc+3][lr]=av.w;
        *(float4*)(&Hs[hr][hc]) = hv;
        __syncthreads();
        #pragma unroll
        for (int kk = 0; kk < 16; ++kk) {
            const float4 a = *(const float4*)(&As[kk][tm]);
            const float4 h = *(const float4*)(&Hs[kk][tn]);
            acc[0][0] += a.x*h.x; acc[0][1] += a.x*h.y; acc[0][2] += a.x*h.z; acc[0][3] += a.x*h.w;
            acc[1][0] += a.y*h.x; acc[1][1] += a.y*h.y; acc[1][2] += a.y*h.z; acc[1][3] += a.y*h.w;
            acc[2][0] += a.z*h.x; acc[2][1] += a.z*h.y; acc[2][2] += a.z*h.z; acc[2][3] += a.z*h.w;
            acc[3][0] += a.w*h.x; acc[3][1] += a.w*h.y; acc[3][2] += a.w*h.z; acc[3][3] += a.w*h.w;
        }
    }
    #pragma unroll
    for (int i = 0; i < 4; ++i) {
        const float mk = mask[b * M + m0 + tm + i];
        float4 o;
        o.x = acc[i][0]*mk; o.y = acc[i][1]*mk; o.z = acc[i][2]*mk; o.w = acc[i][3]*mk;
        if (RELU) { o.x=fmaxf(o.x,0.f); o.y=fmaxf(o.y,0.f); o.z=fmaxf(o.z,0.f); o.w=fmaxf(o.w,0.f); }
        *(float4*)(Y + (size_t)(m0 + tm + i) * Nn + n0 + tn) = o;
    }
}

// ---------------------------------------------------------------------------
__global__ __launch_bounds__(256) void attn_sisj(const float* __restrict__ h,
    const float* __restrict__ aw, const float* __restrict__ ab,
    float* __restrict__ si, float* __restrict__ sj)
{
    const int lane = threadIdx.x & 63;
    const int row  = (blockIdx.x << 2) + (threadIdx.x >> 6);
    const float4 hv = ((const float4*)(h + (size_t)row * HDIM))[lane];
    const float4 a1 = ((const float4*)aw)[lane];
    const float4 a2 = ((const float4*)(aw + HDIM))[lane];
    float s1 = hv.x*a1.x + hv.y*a1.y + hv.z*a1.z + hv.w*a1.w;
    float s2 = hv.x*a2.x + hv.y*a2.y + hv.z*a2.z + hv.w*a2.w;
    #pragma unroll
    for (int off = 32; off > 0; off >>= 1) {
        s1 += __shfl_down(s1, off);
        s2 += __shfl_down(s2, off);
    }
    if (lane == 0) { si[row] = s1 + ab[0]; sj[row] = s2; }
}

// ---------------------------------------------------------------------------
__global__ __launch_bounds__(512) void attn_score(const float* __restrict__ si,
    const float* __restrict__ sj, const float* __restrict__ adj,
    const float* __restrict__ mask, float* __restrict__ watt)
{
    const int bi = blockIdx.x;           // b*NN + i
    const int b  = bi >> 9;
    const int j  = threadIdx.x;
    const float s0 = si[bi];
    const float mi = mask[bi];
    float s = sigmoidf_(s0 + sj[(b << 9) + j]) * adj[(size_t)bi * NN + j] * mi * mask[(b << 9) + j];
    float t = s;
    #pragma unroll
    for (int off = 32; off > 0; off >>= 1) t += __shfl_down(t, off);
    __shared__ float red[8];
    const int lane = j & 63, wv = j >> 6;
    if (lane == 0) red[wv] = t;
    __syncthreads();
    if (j == 0) {
        float tot = 0.f;
        #pragma unroll
        for (int w = 0; w < 8; ++w) tot += red[w];
        red[0] = 1.0f / (tot + 1e-8f);
    }
    __syncthreads();
    watt[(size_t)bi * NN + j] = s * red[0];
}

// ---------------------------------------------------------------------------
// Pack fp32 -> f16x2 (u32). n = element pairs.
// ---------------------------------------------------------------------------
__global__ __launch_bounds__(256) void pack_f16(const float* __restrict__ src,
    unsigned int* __restrict__ dst, int n)
{
    int i = blockIdx.x * 256 + threadIdx.x;
    if (i < n) {
        float2 v = ((const float2*)src)[i];
        _Float16 a = (_Float16)v.x, b = (_Float16)v.y;
        unsigned short ua = *(unsigned short*)&a, ub = *(unsigned short*)&b;
        dst[i] = (unsigned int)ua | ((unsigned int)ub << 16);
    }
}

// ---------------------------------------------------------------------------
// Single-block-per-chain LSTM scan, f16 weights fully CU-resident.
// Grid: 16 blocks (chain = batch*2+dir), 1024 threads (thread = gate row).
// w16: (1024,128) u32 = packed f16 pairs of whh row-major. Per row: u32
// [0..95] live in 24 named uint4 registers; u32 [96..127] live in LDS
// (128 KB, rotation-swizzled so ds_read_b128 is bank-optimal).
// h is kept packed-f16 in LDS (512 B, wave-uniform reads = broadcast).
// Matvec = 128 x v_dot2_f32_f16 per thread (f32 accumulate).
// No inter-block sync at all: 3 __syncthreads per step.
// Dynamic LDS: 32768*4 (weights) + 1024*4 (g) + 128*4 (h2) = 135680 B.
// ---------------------------------------------------------------------------
__global__ __launch_bounds__(1024, 1) void lstm_scan4(
    const float* __restrict__ pre_f, const float* __restrict__ pre_b,
    const unsigned int* __restrict__ w16_f, const unsigned int* __restrict__ w16_b,
    float* __restrict__ out)
{
    extern __shared__ unsigned int smem[];
    unsigned int* lw = smem;                       // [1024][32] swizzled
    float* g_s = (float*)(smem + 32768);           // [1024]
    unsigned int* h2 = smem + 32768 + 1024;        // [128] packed half2

    const int chain = blockIdx.x;
    const int batch = chain >> 1;
    const int dir   = chain & 1;
    const float* pre = dir ? pre_b : pre_f;
    const unsigned int* w = dir ? w16_b : w16_f;
    const int t0 = threadIdx.x;                    // gate row 0..1023

    const uint4* wr = (const uint4*)(w + (size_t)t0 * 128);
#define WD(i) const uint4 W##i = wr[i];
    WD(0) WD(1) WD(2) WD(3) WD(4) WD(5) WD(6) WD(7) WD(8) WD(9) WD(10) WD(11)
    WD(12) WD(13) WD(14) WD(15) WD(16) WD(17) WD(18) WD(19) WD(20) WD(21) WD(22) WD(23)
#undef WD
    const int rot = t0 & 7;
    {
        #pragma unroll
        for (int i = 0; i < 8; ++i) {
            uint4 v = wr[24 + i];
            *(uint4*)&lw[t0 * 32 + (((i + rot) & 7) << 2)] = v;
        }
    }
    if (t0 < 128) h2[t0] = 0u;
    float c = 0.f;

    const int tt0 = dir ? (TT - 1) : 0;
    const long pstep = dir ? -1024 : 1024;
    const long ostep = dir ? -512 : 512;
    const float* pp = pre + ((size_t)batch * TT + tt0) * 1024 + t0;
    float* op = out + ((size_t)batch * TT + tt0) * 512 + dir * 256 + t0;  // used by t0<256
    float pv = *pp;
    pp += pstep;
    __syncthreads();

    for (int t = 0; t < TT; ++t) {
        float a0 = 0.f, a1 = 0.f, a2 = 0.f, a3 = 0.f;
        const uint4* h4 = (const uint4*)h2;
#define DOTA(i) { const uint4 hv = h4[i]; \
        a0 = fdot2_(W##i.x, hv.x, a0); a1 = fdot2_(W##i.y, hv.y, a1); \
        a2 = fdot2_(W##i.z, hv.z, a2); a3 = fdot2_(W##i.w, hv.w, a3); }
        DOTA(0) DOTA(1) DOTA(2) DOTA(3) DOTA(4) DOTA(5) DOTA(6) DOTA(7)
        DOTA(8) DOTA(9) DOTA(10) DOTA(11) DOTA(12) DOTA(13) DOTA(14) DOTA(15)
        DOTA(16) DOTA(17) DOTA(18) DOTA(19) DOTA(20) DOTA(21) DOTA(22) DOTA(23)
#undef DOTA
        #pragma unroll
        for (int i = 0; i < 8; ++i) {
            const uint4 wv = *(const uint4*)&lw[t0 * 32 + (((i + rot) & 7) << 2)];
            const uint4 hv = h4[24 + i];
            a0 = fdot2_(wv.x, hv.x, a0); a1 = fdot2_(wv.y, hv.y, a1);
            a2 = fdot2_(wv.z, hv.z, a2); a3 = fdot2_(wv.w, hv.w, a3);
        }
        float pv_next = 0.f;
        if (t + 1 < TT) pv_next = *pp;
        pp += pstep;
        g_s[t0] = (a0 + a1) + (a2 + a3) + pv;
        __syncthreads();
        if (t0 < 256) {
            const float ig = sigmoidf_(g_s[t0]);
            const float fg = sigmoidf_(g_s[256 + t0]);
            const float gg = tanhf_(g_s[512 + t0]);
            const float og = sigmoidf_(g_s[768 + t0]);
            c = fg * c + ig * gg;
            const float h = og * tanhf_(c);
            *op = h;
            op += ostep;
            _Float16 hh = (_Float16)h;
            ((unsigned short*)h2)[t0] = *(unsigned short*)&hh;
        }
        pv = pv_next;
        __syncthreads();
    }
}

// ---------------------------------------------------------------------------

extern "C" void kernel_launch(void* const* d_in, const int* in_sizes, int n_in,
                              void* d_out, int out_size, void* d_ws, size_t ws_size,
                              hipStream_t stream)
{
    const float* nf   = (const float*)d_in[0];
    const float* adj  = (const float*)d_in[1];
    const float* mask = (const float*)d_in[2];
    const float* g_w[3]  = {(const float*)d_in[4],  (const float*)d_in[8],  (const float*)d_in[12]};
    const float* g_b[3]  = {(const float*)d_in[5],  (const float*)d_in[9],  (const float*)d_in[13]};
    const float* g_aw[3] = {(const float*)d_in[6],  (const float*)d_in[10], (const float*)d_in[14]};
    const float* g_ab[3] = {(const float*)d_in[7],  (const float*)d_in[11], (const float*)d_in[15]};
    const float* wih0f = (const float*)d_in[16]; const float* whh0f = (const float*)d_in[17]; const float* b0f = (const float*)d_in[18];
    const float* wih0b = (const float*)d_in[19]; const float* whh0b = (const float*)d_in[20]; const float* b0b = (const float*)d_in[21];
    const float* wih1f = (const float*)d_in[22]; const float* whh1f = (const float*)d_in[23]; const float* b1f = (const float*)d_in[24];
    const float* wih1b = (const float*)d_in[25]; const float* whh1b = (const float*)d_in[26]; const float* b1b = (const float*)d_in[27];

    float* ws = (float*)d_ws;
    // Workspace layout (floats); total ~15.7M floats = ~63 MB
    float* bufA = ws;                       // (4096,256)  GNN h projection / head tmp
    float* bufB = bufA + 1048576;           // (4096,256)  GNN layer output; later f16 weights
    float* bufC = bufB + 1048576;           // (4096,256)  GNN3 output (kept for nd head)
    float* si   = bufC + 1048576;           // (4096)
    float* sj   = si + 4096;                // (4096)
    float* out0 = sj + 4096;                // (4096,512) LSTM layer0 output
    float* out1 = out0 + 2097152;           // (4096,512) LSTM layer1 output
    float* P0   = out1 + 2097152;           // (4096,1024) pre-activations fwd
    float* P1   = P0 + 4194304;             // (4096,1024) pre-activations bwd
    float* watt = P0;                       // alias: attention weights (GNN phase only)
    // packed f16 whh weights, aliased onto bufB (dead after GNN3):
    unsigned int* w16_0f = (unsigned int*)bufB;
    unsigned int* w16_0b = w16_0f + 131072;
    unsigned int* w16_1f = w16_0b + 131072;
    unsigned int* w16_1b = w16_1f + 131072;

    const int MR = BB * NN;                 // 4096 rows
    dim3 blk(256);
    const int SCAN_LDS = (32768 + 1024 + 128) * 4;   // 135680 B

    // ---------------- GNN x3 ----------------
    auto run_gnn = [&](const float* xin, int Kin, int li, float* ob, bool relu) {
        gemm_nt<0><<<dim3(HDIM / 64, MR / 64), blk, 0, stream>>>(xin, g_w[li], g_b[li], bufA, MR, Kin, HDIM);
        attn_sisj<<<dim3(MR / 4), blk, 0, stream>>>(bufA, g_aw[li], g_ab[li], si, sj);
        attn_score<<<dim3(MR), dim3(512), 0, stream>>>(si, sj, adj, mask, watt);
        if (relu)
            gemm_nn_mask<1><<<dim3(HDIM / 64, NN / 64, BB), blk, 0, stream>>>(watt, bufA, mask, ob, NN, NN, HDIM);
        else
            gemm_nn_mask<0><<<dim3(HDIM / 64, NN / 64, BB), blk, 0, stream>>>(watt, bufA, mask, ob, NN, NN, HDIM);
    };
    run_gnn(nf,   NDIM, 0, bufB, true);
    run_gnn(bufB, HDIM, 1, bufB, true);
    run_gnn(bufB, HDIM, 2, bufC, false);

    // ---------------- pack whh weights to f16 (bufB now dead) ----------------
    pack_f16<<<dim3(512), blk, 0, stream>>>(whh0f, w16_0f, 131072);
    pack_f16<<<dim3(512), blk, 0, stream>>>(whh0b, w16_0b, 131072);
    pack_f16<<<dim3(512), blk, 0, stream>>>(whh1f, w16_1f, 131072);
    pack_f16<<<dim3(512), blk, 0, stream>>>(whh1b, w16_1b, 131072);

    // ---------------- LSTM layer 0 ----------------
    gemm_nt<0><<<dim3(16, MR / 64), blk, 0, stream>>>(bufC, wih0f, b0f, P0, MR, HDIM, 1024);
    gemm_nt<0><<<dim3(16, MR / 64), blk, 0, stream>>>(bufC, wih0b, b0b, P1, MR, HDIM, 1024);
    lstm_scan4<<<dim3(16), dim3(1024), SCAN_LDS, stream>>>(P0, P1, w16_0f, w16_0b, out0);

    // ---------------- LSTM layer 1 ----------------
    gemm_nt<0><<<dim3(16, MR / 64), blk, 0, stream>>>(out0, wih1f, b1f, P0, MR, 512, 1024);
    gemm_nt<0><<<dim3(16, MR / 64), blk, 0, stream>>>(out0, wih1b, b1b, P1, MR, 512, 1024);
    lstm_scan4<<<dim3(16), dim3(1024), SCAN_LDS, stream>>>(P0, P1, w16_1f, w16_1b, out1);

    // ---------------- Heads ----------------
    float* out = (float*)d_out;
    // op: (B,N,64) at offset 0
    gemm_nt<1><<<dim3(4, MR / 64), blk, 0, stream>>>(out1, (const float*)d_in[28], (const float*)d_in[29], bufA, MR, 512, 256);
    gemm_nt<0><<<dim3(1, MR / 64), blk, 0, stream>>>(bufA, (const float*)d_in[30], (const float*)d_in[31], out, MR, 256, 64);
    // pp: (B,N,16) at offset 262144
    gemm_nt<1><<<dim3(4, MR / 64), blk, 0, stream>>>(out1, (const float*)d_in[32], (const float*)d_in[33], bufA, MR, 512, 256);
    gemm_nt<0><<<dim3(1, MR / 64), blk, 0, stream>>>(bufA, (const float*)d_in[34], (const float*)d_in[35], out + 262144, MR, 256, 16);
    // sk: (B,N,128) at offset 327680
    gemm_nt<1><<<dim3(4, MR / 64), blk, 0, stream>>>(out1, (const float*)d_in[36], (const float*)d_in[37], bufA, MR, 512, 256);
    gemm_nt<0><<<dim3(2, MR / 64), blk, 0, stream>>>(bufA, (const float*)d_in[38], (const float*)d_in[39], out + 327680, MR, 256, 128);
    // nd: (B,N,128) at offset 851968 (input = GNN3 output)
    gemm_nt<1><<<dim3(4, MR / 64), blk, 0, stream>>>(bufC, (const float*)d_in[40], (const float*)d_in[41], bufA, MR, 256, 256);
    gemm_nt<0><<<dim3(2, MR / 64), blk, 0, stream>>>(bufA, (const float*)d_in[42], (const float*)d_in[43], out + 851968, MR, 256, 128);
}

// Round 6
// 2622.237 us; speedup vs baseline: 2.5217x; 1.7353x over previous
//
#include <hip/hip_runtime.h>

// Problem constants (DeepCAD_1958505087412)
#define BB   8
#define NN   512      // nodes == timesteps
#define NDIM 128
#define HDIM 256      // GNN out dim == LSTM hidden
#define TT   512

__device__ __forceinline__ float sigmoidf_(float x) { return 1.0f / (1.0f + __expf(-x)); }
__device__ __forceinline__ float tanhf_(float x) { float e = __expf(2.0f * x); return 1.0f - 2.0f / (e + 1.0f); }

typedef _Float16 half2v __attribute__((ext_vector_type(2)));
typedef unsigned int uint4v __attribute__((ext_vector_type(4)));
__device__ __forceinline__ float fdot2_(unsigned int w, unsigned int h, float acc) {
    return __builtin_amdgcn_fdot2(__builtin_bit_cast(half2v, w),
                                  __builtin_bit_cast(half2v, h), acc, false);
}

// ---------------------------------------------------------------------------
// Y = X @ W^T + bias (optional ReLU). X:(M,K) W:(Nn,K) Y:(M,Nn) row-major.
// ---------------------------------------------------------------------------
template<int RELU>
__global__ __launch_bounds__(256) void gemm_nt(const float* __restrict__ X,
    const float* __restrict__ W, const float* __restrict__ bias,
    float* __restrict__ Y, int M, int K, int Nn)
{
    __shared__ float Xs[16][68];
    __shared__ float Ws[16][68];
    const int tid = threadIdx.x;
    const int m0 = blockIdx.y << 6;
    const int n0 = blockIdx.x << 6;
    const int lr = tid >> 2;           // 0..63
    const int lc = (tid & 3) << 2;     // 0,4,8,12
    const int tm = (tid >> 4) << 2;    // 0..60
    const int tn = (tid & 15) << 2;    // 0..60

    float acc[4][4] = {{0.f,0.f,0.f,0.f},{0.f,0.f,0.f,0.f},{0.f,0.f,0.f,0.f},{0.f,0.f,0.f,0.f}};

    const float* Xp = X + (size_t)(m0 + lr) * K + lc;
    const bool wok = (n0 + lr) < Nn;
    const float* Wp = wok ? (W + (size_t)(n0 + lr) * K + lc) : W;

    for (int k0 = 0; k0 < K; k0 += 16) {
        float4 xv = *(const float4*)(Xp + k0);
        float4 wv = *(const float4*)(Wp + k0);
        if (!wok) wv = make_float4(0.f, 0.f, 0.f, 0.f);
        __syncthreads();
        Xs[lc+0][lr]=xv.x; Xs[lc+1][lr]=xv.y; Xs[lc+2][lr]=xv.z; Xs[lc+3][lr]=xv.w;
        Ws[lc+0][lr]=wv.x; Ws[lc+1][lr]=wv.y; Ws[lc+2][lr]=wv.z; Ws[lc+3][lr]=wv.w;
        __syncthreads();
        #pragma unroll
        for (int kk = 0; kk < 16; ++kk) {
            const float4 a = *(const float4*)(&Xs[kk][tm]);
            const float4 b = *(const float4*)(&Ws[kk][tn]);
            acc[0][0] += a.x*b.x; acc[0][1] += a.x*b.y; acc[0][2] += a.x*b.z; acc[0][3] += a.x*b.w;
            acc[1][0] += a.y*b.x; acc[1][1] += a.y*b.y; acc[1][2] += a.y*b.z; acc[1][3] += a.y*b.w;
            acc[2][0] += a.z*b.x; acc[2][1] += a.z*b.y; acc[2][2] += a.z*b.z; acc[2][3] += a.z*b.w;
            acc[3][0] += a.w*b.x; acc[3][1] += a.w*b.y; acc[3][2] += a.w*b.z; acc[3][3] += a.w*b.w;
        }
    }
    const int nc = n0 + tn;
    if (nc >= Nn) return;
    float4 bv = make_float4(0.f, 0.f, 0.f, 0.f);
    if (bias) bv = *(const float4*)(bias + nc);
    #pragma unroll
    for (int i = 0; i < 4; ++i) {
        float4 o;
        o.x = acc[i][0] + bv.x; o.y = acc[i][1] + bv.y;
        o.z = acc[i][2] + bv.z; o.w = acc[i][3] + bv.w;
        if (RELU) { o.x=fmaxf(o.x,0.f); o.y=fmaxf(o.y,0.f); o.z=fmaxf(o.z,0.f); o.w=fmaxf(o.w,0.f); }
        *(float4*)(Y + (size_t)(m0 + tm + i) * Nn + nc) = o;
    }
}

// ---------------------------------------------------------------------------
// Batched Y[b] = (A[b] @ H[b]) * mask[b,:,None], optional ReLU.
// ---------------------------------------------------------------------------
template<int RELU>
__global__ __launch_bounds__(256) void gemm_nn_mask(const float* __restrict__ A,
    const float* __restrict__ Hm, const float* __restrict__ mask,
    float* __restrict__ Y, int M, int K, int Nn)
{
    const int b = blockIdx.z;
    A  += (size_t)b * M * K;
    Hm += (size_t)b * K * Nn;
    Y  += (size_t)b * M * Nn;
    __shared__ float As[16][68];
    __shared__ float Hs[16][68];
    const int tid = threadIdx.x;
    const int m0 = blockIdx.y << 6;
    const int n0 = blockIdx.x << 6;
    const int lr = tid >> 2;
    const int lc = (tid & 3) << 2;
    const int hr = tid >> 4;           // 0..15
    const int hc = (tid & 15) << 2;    // 0..60
    const int tm = (tid >> 4) << 2;
    const int tn = (tid & 15) << 2;

    float acc[4][4] = {{0.f,0.f,0.f,0.f},{0.f,0.f,0.f,0.f},{0.f,0.f,0.f,0.f},{0.f,0.f,0.f,0.f}};

    for (int k0 = 0; k0 < K; k0 += 16) {
        float4 av = *(const float4*)(A + (size_t)(m0 + lr) * K + k0 + lc);
        float4 hv = *(const float4*)(Hm + (size_t)(k0 + hr) * Nn + n0 + hc);
        __syncthreads();
        As[lc+0][lr]=av.x; As[lc+1][lr]=av.y; As[lc+2][lr]=av.z; As[lc+3][lr]=av.w;
        *(float4*)(&Hs[hr][hc]) = hv;
        __syncthreads();
        #pragma unroll
        for (int kk = 0; kk < 16; ++kk) {
            const float4 a = *(const float4*)(&As[kk][tm]);
            const float4 h = *(const float4*)(&Hs[kk][tn]);
            acc[0][0] += a.x*h.x; acc[0][1] += a.x*h.y; acc[0][2] += a.x*h.z; acc[0][3] += a.x*h.w;
            acc[1][0] += a.y*h.x; acc[1][1] += a.y*h.y; acc[1][2] += a.y*h.z; acc[1][3] += a.y*h.w;
            acc[2][0] += a.z*h.x; acc[2][1] += a.z*h.y; acc[2][2] += a.z*h.z; acc[2][3] += a.z*h.w;
            acc[3][0] += a.w*h.x; acc[3][1] += a.w*h.y; acc[3][2] += a.w*h.z; acc[3][3] += a.w*h.w;
        }
    }
    #pragma unroll
    for (int i = 0; i < 4; ++i) {
        const float mk = mask[b * M + m0 + tm + i];
        float4 o;
        o.x = acc[i][0]*mk; o.y = acc[i][1]*mk; o.z = acc[i][2]*mk; o.w = acc[i][3]*mk;
        if (RELU) { o.x=fmaxf(o.x,0.f); o.y=fmaxf(o.y,0.f); o.z=fmaxf(o.z,0.f); o.w=fmaxf(o.w,0.f); }
        *(float4*)(Y + (size_t)(m0 + tm + i) * Nn + n0 + tn) = o;
    }
}

// ---------------------------------------------------------------------------
__global__ __launch_bounds__(256) void attn_sisj(const float* __restrict__ h,
    const float* __restrict__ aw, const float* __restrict__ ab,
    float* __restrict__ si, float* __restrict__ sj)
{
    const int lane = threadIdx.x & 63;
    const int row  = (blockIdx.x << 2) + (threadIdx.x >> 6);
    const float4 hv = ((const float4*)(h + (size_t)row * HDIM))[lane];
    const float4 a1 = ((const float4*)aw)[lane];
    const float4 a2 = ((const float4*)(aw + HDIM))[lane];
    float s1 = hv.x*a1.x + hv.y*a1.y + hv.z*a1.z + hv.w*a1.w;
    float s2 = hv.x*a2.x + hv.y*a2.y + hv.z*a2.z + hv.w*a2.w;
    #pragma unroll
    for (int off = 32; off > 0; off >>= 1) {
        s1 += __shfl_down(s1, off);
        s2 += __shfl_down(s2, off);
    }
    if (lane == 0) { si[row] = s1 + ab[0]; sj[row] = s2; }
}

// ---------------------------------------------------------------------------
__global__ __launch_bounds__(512) void attn_score(const float* __restrict__ si,
    const float* __restrict__ sj, const float* __restrict__ adj,
    const float* __restrict__ mask, float* __restrict__ watt)
{
    const int bi = blockIdx.x;           // b*NN + i
    const int b  = bi >> 9;
    const int j  = threadIdx.x;
    const float s0 = si[bi];
    const float mi = mask[bi];
    float s = sigmoidf_(s0 + sj[(b << 9) + j]) * adj[(size_t)bi * NN + j] * mi * mask[(b << 9) + j];
    float t = s;
    #pragma unroll
    for (int off = 32; off > 0; off >>= 1) t += __shfl_down(t, off);
    __shared__ float red[8];
    const int lane = j & 63, wv = j >> 6;
    if (lane == 0) red[wv] = t;
    __syncthreads();
    if (j == 0) {
        float tot = 0.f;
        #pragma unroll
        for (int w = 0; w < 8; ++w) tot += red[w];
        red[0] = 1.0f / (tot + 1e-8f);
    }
    __syncthreads();
    watt[(size_t)bi * NN + j] = s * red[0];
}

// ---------------------------------------------------------------------------
// Pack fp32 -> f16x2 (u32). n = element pairs.
// ---------------------------------------------------------------------------
__global__ __launch_bounds__(256) void pack_f16(const float* __restrict__ src,
    unsigned int* __restrict__ dst, int n)
{
    int i = blockIdx.x * 256 + threadIdx.x;
    if (i < n) {
        float2 v = ((const float2*)src)[i];
        _Float16 a = (_Float16)v.x, b = (_Float16)v.y;
        unsigned short ua = *(unsigned short*)&a, ub = *(unsigned short*)&b;
        dst[i] = (unsigned int)ua | ((unsigned int)ub << 16);
    }
}

// ---------------------------------------------------------------------------
// Single-block-per-chain LSTM scan, f16 weights CU-resident.
// Grid: 16 blocks (chain = batch*2+dir), 512 threads, launch_bounds(512,2)
// -> 2 waves/SIMD -> 256-VGPR budget. Thread t owns gate rows t and 512+t:
// per row, u32[0..23] of the 32 uint4s live in NAMED registers (48 uint4 =
// 192 VGPRs, pinned live with volatile asm so RA cannot rematerialize the
// loads), u32[24..31] live in LDS laid out lw4[i][tid] (lane-contiguous ->
// conflict-free ds_read_b128). h is packed f16 in LDS (broadcast reads).
// Matvec = 256 x v_dot2_f32_f16 per thread per step, 8 accumulators.
// 2 __syncthreads per step, no inter-block sync.
// Dynamic LDS: 16*512*16 (weights) + 1024*4 (g) + 128*4 (h2) = 135680 B.
// ---------------------------------------------------------------------------
__global__ __launch_bounds__(512, 2) void lstm_scan5(
    const float* __restrict__ pre_f, const float* __restrict__ pre_b,
    const unsigned int* __restrict__ w16_f, const unsigned int* __restrict__ w16_b,
    float* __restrict__ out)
{
    extern __shared__ unsigned int smem[];
    uint4v* lw4 = (uint4v*)smem;                   // [16][512] uint4
    float* g_s = (float*)(smem + 32768);           // [1024]
    unsigned int* h2 = smem + 32768 + 1024;        // [128] packed half2

    const int chain = blockIdx.x;
    const int batch = chain >> 1;
    const int dir   = chain & 1;
    const float* pre = dir ? pre_b : pre_f;
    const unsigned int* w = dir ? w16_b : w16_f;
    const int t0 = threadIdx.x;                    // 0..511

    const uint4v* wrA = (const uint4v*)(w + (size_t)t0 * 128);          // row t0
    const uint4v* wrB = (const uint4v*)(w + (size_t)(t0 + 512) * 128);  // row t0+512

#define WD(i) uint4v A##i = wrA[i]; uint4v B##i = wrB[i];
    WD(0) WD(1) WD(2) WD(3) WD(4) WD(5) WD(6) WD(7) WD(8) WD(9) WD(10) WD(11)
    WD(12) WD(13) WD(14) WD(15) WD(16) WD(17) WD(18) WD(19) WD(20) WD(21) WD(22) WD(23)
#undef WD
    // Pin: volatile asm results cannot be rematerialized -> weights stay in VGPRs.
#define PIN(x) asm volatile("" : "+v"(x));
    PIN(A0) PIN(A1) PIN(A2) PIN(A3) PIN(A4) PIN(A5) PIN(A6) PIN(A7) PIN(A8) PIN(A9)
    PIN(A10) PIN(A11) PIN(A12) PIN(A13) PIN(A14) PIN(A15) PIN(A16) PIN(A17) PIN(A18)
    PIN(A19) PIN(A20) PIN(A21) PIN(A22) PIN(A23)
    PIN(B0) PIN(B1) PIN(B2) PIN(B3) PIN(B4) PIN(B5) PIN(B6) PIN(B7) PIN(B8) PIN(B9)
    PIN(B10) PIN(B11) PIN(B12) PIN(B13) PIN(B14) PIN(B15) PIN(B16) PIN(B17) PIN(B18)
    PIN(B19) PIN(B20) PIN(B21) PIN(B22) PIN(B23)
#undef PIN

    // LDS tail: uint4 24..31 of each row, lane-contiguous layout.
    #pragma unroll
    for (int i = 0; i < 8; ++i) {
        lw4[i * 512 + t0]       = wrA[24 + i];
        lw4[(8 + i) * 512 + t0] = wrB[24 + i];
    }
    if (t0 < 128) h2[t0] = 0u;
    float c = 0.f;

    const int tt0 = dir ? (TT - 1) : 0;
    const long pstep = dir ? -1024 : 1024;
    const long ostep = dir ? -512 : 512;
    const float* ppA = pre + ((size_t)batch * TT + tt0) * 1024 + t0;
    const float* ppB = ppA + 512;
    float* op = out + ((size_t)batch * TT + tt0) * 512 + dir * 256 + t0;  // used by t0<256
    float pvA = *ppA; ppA += pstep;
    float pvB = *ppB; ppB += pstep;
    __syncthreads();

    for (int t = 0; t < TT; ++t) {
        // prefetch next step's pre values early (hidden under the dots)
        float pvA_n = 0.f, pvB_n = 0.f;
        if (t + 1 < TT) { pvA_n = *ppA; pvB_n = *ppB; }
        ppA += pstep; ppB += pstep;

        float a0 = 0.f, a1 = 0.f, a2 = 0.f, a3 = 0.f;
        float b0 = 0.f, b1 = 0.f, b2 = 0.f, b3 = 0.f;
        const uint4v* h4 = (const uint4v*)h2;
#define DOT2(i) { const uint4v hv = h4[i]; \
        a0 = fdot2_(A##i.x, hv.x, a0); a1 = fdot2_(A##i.y, hv.y, a1); \
        a2 = fdot2_(A##i.z, hv.z, a2); a3 = fdot2_(A##i.w, hv.w, a3); \
        b0 = fdot2_(B##i.x, hv.x, b0); b1 = fdot2_(B##i.y, hv.y, b1); \
        b2 = fdot2_(B##i.z, hv.z, b2); b3 = fdot2_(B##i.w, hv.w, b3); }
        DOT2(0) DOT2(1) DOT2(2) DOT2(3) DOT2(4) DOT2(5) DOT2(6) DOT2(7)
        DOT2(8) DOT2(9) DOT2(10) DOT2(11) DOT2(12) DOT2(13) DOT2(14) DOT2(15)
        DOT2(16) DOT2(17) DOT2(18) DOT2(19) DOT2(20) DOT2(21) DOT2(22) DOT2(23)
#undef DOT2
        #pragma unroll
        for (int i = 0; i < 8; ++i) {
            const uint4v wa = lw4[i * 512 + t0];
            const uint4v wb = lw4[(8 + i) * 512 + t0];
            const uint4v hv = h4[24 + i];
            a0 = fdot2_(wa.x, hv.x, a0); a1 = fdot2_(wa.y, hv.y, a1);
            a2 = fdot2_(wa.z, hv.z, a2); a3 = fdot2_(wa.w, hv.w, a3);
            b0 = fdot2_(wb.x, hv.x, b0); b1 = fdot2_(wb.y, hv.y, b1);
            b2 = fdot2_(wb.z, hv.z, b2); b3 = fdot2_(wb.w, hv.w, b3);
        }
        g_s[t0]       = (a0 + a1) + (a2 + a3) + pvA;
        g_s[512 + t0] = (b0 + b1) + (b2 + b3) + pvB;
        __syncthreads();
        if (t0 < 256) {
            const float ig = sigmoidf_(g_s[t0]);
            const float fg = sigmoidf_(g_s[256 + t0]);
            const float gg = tanhf_(g_s[512 + t0]);
            const float og = sigmoidf_(g_s[768 + t0]);
            c = fg * c + ig * gg;
            const float h = og * tanhf_(c);
            *op = h;
            op += ostep;
            _Float16 hh = (_Float16)h;
            ((unsigned short*)h2)[t0] = *(unsigned short*)&hh;
        }
        pvA = pvA_n; pvB = pvB_n;
        __syncthreads();
    }
}

// ---------------------------------------------------------------------------

extern "C" void kernel_launch(void* const* d_in, const int* in_sizes, int n_in,
                              void* d_out, int out_size, void* d_ws, size_t ws_size,
                              hipStream_t stream)
{
    const float* nf   = (const float*)d_in[0];
    const float* adj  = (const float*)d_in[1];
    const float* mask = (const float*)d_in[2];
    const float* g_w[3]  = {(const float*)d_in[4],  (const float*)d_in[8],  (const float*)d_in[12]};
    const float* g_b[3]  = {(const float*)d_in[5],  (const float*)d_in[9],  (const float*)d_in[13]};
    const float* g_aw[3] = {(const float*)d_in[6],  (const float*)d_in[10], (const float*)d_in[14]};
    const float* g_ab[3] = {(const float*)d_in[7],  (const float*)d_in[11], (const float*)d_in[15]};
    const float* wih0f = (const float*)d_in[16]; const float* whh0f = (const float*)d_in[17]; const float* b0f = (const float*)d_in[18];
    const float* wih0b = (const float*)d_in[19]; const float* whh0b = (const float*)d_in[20]; const float* b0b = (const float*)d_in[21];
    const float* wih1f = (const float*)d_in[22]; const float* whh1f = (const float*)d_in[23]; const float* b1f = (const float*)d_in[24];
    const float* wih1b = (const float*)d_in[25]; const float* whh1b = (const float*)d_in[26]; const float* b1b = (const float*)d_in[27];

    float* ws = (float*)d_ws;
    // Workspace layout (floats); total ~15.7M floats = ~63 MB
    float* bufA = ws;                       // (4096,256)  GNN h projection / head tmp
    float* bufB = bufA + 1048576;           // (4096,256)  GNN layer output; later f16 weights
    float* bufC = bufB + 1048576;           // (4096,256)  GNN3 output (kept for nd head)
    float* si   = bufC + 1048576;           // (4096)
    float* sj   = si + 4096;                // (4096)
    float* out0 = sj + 4096;                // (4096,512) LSTM layer0 output
    float* out1 = out0 + 2097152;           // (4096,512) LSTM layer1 output
    float* P0   = out1 + 2097152;           // (4096,1024) pre-activations fwd
    float* P1   = P0 + 4194304;             // (4096,1024) pre-activations bwd
    float* watt = P0;                       // alias: attention weights (GNN phase only)
    // packed f16 whh weights, aliased onto bufB (dead after GNN3):
    unsigned int* w16_0f = (unsigned int*)bufB;
    unsigned int* w16_0b = w16_0f + 131072;
    unsigned int* w16_1f = w16_0b + 131072;
    unsigned int* w16_1b = w16_1f + 131072;

    const int MR = BB * NN;                 // 4096 rows
    dim3 blk(256);
    const int SCAN_LDS = (32768 + 1024 + 128) * 4;   // 135680 B

    // ---------------- GNN x3 ----------------
    auto run_gnn = [&](const float* xin, int Kin, int li, float* ob, bool relu) {
        gemm_nt<0><<<dim3(HDIM / 64, MR / 64), blk, 0, stream>>>(xin, g_w[li], g_b[li], bufA, MR, Kin, HDIM);
        attn_sisj<<<dim3(MR / 4), blk, 0, stream>>>(bufA, g_aw[li], g_ab[li], si, sj);
        attn_score<<<dim3(MR), dim3(512), 0, stream>>>(si, sj, adj, mask, watt);
        if (relu)
            gemm_nn_mask<1><<<dim3(HDIM / 64, NN / 64, BB), blk, 0, stream>>>(watt, bufA, mask, ob, NN, NN, HDIM);
        else
            gemm_nn_mask<0><<<dim3(HDIM / 64, NN / 64, BB), blk, 0, stream>>>(watt, bufA, mask, ob, NN, NN, HDIM);
    };
    run_gnn(nf,   NDIM, 0, bufB, true);
    run_gnn(bufB, HDIM, 1, bufB, true);
    run_gnn(bufB, HDIM, 2, bufC, false);

    // ---------------- pack whh weights to f16 (bufB now dead) ----------------
    pack_f16<<<dim3(512), blk, 0, stream>>>(whh0f, w16_0f, 131072);
    pack_f16<<<dim3(512), blk, 0, stream>>>(whh0b, w16_0b, 131072);
    pack_f16<<<dim3(512), blk, 0, stream>>>(whh1f, w16_1f, 131072);
    pack_f16<<<dim3(512), blk, 0, stream>>>(whh1b, w16_1b, 131072);

    // ---------------- LSTM layer 0 ----------------
    gemm_nt<0><<<dim3(16, MR / 64), blk, 0, stream>>>(bufC, wih0f, b0f, P0, MR, HDIM, 1024);
    gemm_nt<0><<<dim3(16, MR / 64), blk, 0, stream>>>(bufC, wih0b, b0b, P1, MR, HDIM, 1024);
    lstm_scan5<<<dim3(16), dim3(512), SCAN_LDS, stream>>>(P0, P1, w16_0f, w16_0b, out0);

    // ---------------- LSTM layer 1 ----------------
    gemm_nt<0><<<dim3(16, MR / 64), blk, 0, stream>>>(out0, wih1f, b1f, P0, MR, 512, 1024);
    gemm_nt<0><<<dim3(16, MR / 64), blk, 0, stream>>>(out0, wih1b, b1b, P1, MR, 512, 1024);
    lstm_scan5<<<dim3(16), dim3(512), SCAN_LDS, stream>>>(P0, P1, w16_1f, w16_1b, out1);

    // ---------------- Heads ----------------
    float* out = (float*)d_out;
    // op: (B,N,64) at offset 0
    gemm_nt<1><<<dim3(4, MR / 64), blk, 0, stream>>>(out1, (const float*)d_in[28], (const float*)d_in[29], bufA, MR, 512, 256);
    gemm_nt<0><<<dim3(1, MR / 64), blk, 0, stream>>>(bufA, (const float*)d_in[30], (const float*)d_in[31], out, MR, 256, 64);
    // pp: (B,N,16) at offset 262144
    gemm_nt<1><<<dim3(4, MR / 64), blk, 0, stream>>>(out1, (const float*)d_in[32], (const float*)d_in[33], bufA, MR, 512, 256);
    gemm_nt<0><<<dim3(1, MR / 64), blk, 0, stream>>>(bufA, (const float*)d_in[34], (const float*)d_in[35], out + 262144, MR, 256, 16);
    // sk: (B,N,128) at offset 327680
    gemm_nt<1><<<dim3(4, MR / 64), blk, 0, stream>>>(out1, (const float*)d_in[36], (const float*)d_in[37], bufA, MR, 512, 256);
    gemm_nt<0><<<dim3(2, MR / 64), blk, 0, stream>>>(bufA, (const float*)d_in[38], (const float*)d_in[39], out + 327680, MR, 256, 128);
    // nd: (B,N,128) at offset 851968 (input = GNN3 output)
    gemm_nt<1><<<dim3(4, MR / 64), blk, 0, stream>>>(bufC, (const float*)d_in[40], (const float*)d_in[41], bufA, MR, 256, 256);
    gemm_nt<0><<<dim3(2, MR / 64), blk, 0, stream>>>(bufA, (const float*)d_in[42], (const float*)d_in[43], out + 851968, MR, 256, 128);
}

// Round 7
// 2596.110 us; speedup vs baseline: 2.5471x; 1.0101x over previous
//
#include <hip/hip_runtime.h>

// Problem constants (DeepCAD_1958505087412)
#define BB   8
#define NN   512      // nodes == timesteps
#define NDIM 128
#define HDIM 256      // GNN out dim == LSTM hidden
#define TT   512

__device__ __forceinline__ float sigmoidf_(float x) { return 1.0f / (1.0f + __expf(-x)); }
__device__ __forceinline__ float tanhf_(float x) { float e = __expf(2.0f * x); return 1.0f - 2.0f / (e + 1.0f); }

typedef _Float16 half2v __attribute__((ext_vector_type(2)));
typedef unsigned int uint4v __attribute__((ext_vector_type(4)));
__device__ __forceinline__ float fdot2_(unsigned int w, unsigned int h, float acc) {
    return __builtin_amdgcn_fdot2(__builtin_bit_cast(half2v, w),
                                  __builtin_bit_cast(half2v, h), acc, false);
}

// ---------------------------------------------------------------------------
// Y = X @ W^T + bias (optional ReLU). X:(M,K) W:(Nn,K) Y:(M,Nn) row-major.
// ---------------------------------------------------------------------------
template<int RELU>
__global__ __launch_bounds__(256) void gemm_nt(const float* __restrict__ X,
    const float* __restrict__ W, const float* __restrict__ bias,
    float* __restrict__ Y, int M, int K, int Nn)
{
    __shared__ float Xs[16][68];
    __shared__ float Ws[16][68];
    const int tid = threadIdx.x;
    const int m0 = blockIdx.y << 6;
    const int n0 = blockIdx.x << 6;
    const int lr = tid >> 2;           // 0..63
    const int lc = (tid & 3) << 2;     // 0,4,8,12
    const int tm = (tid >> 4) << 2;    // 0..60
    const int tn = (tid & 15) << 2;    // 0..60

    float acc[4][4] = {{0.f,0.f,0.f,0.f},{0.f,0.f,0.f,0.f},{0.f,0.f,0.f,0.f},{0.f,0.f,0.f,0.f}};

    const float* Xp = X + (size_t)(m0 + lr) * K + lc;
    const bool wok = (n0 + lr) < Nn;
    const float* Wp = wok ? (W + (size_t)(n0 + lr) * K + lc) : W;

    for (int k0 = 0; k0 < K; k0 += 16) {
        float4 xv = *(const float4*)(Xp + k0);
        float4 wv = *(const float4*)(Wp + k0);
        if (!wok) wv = make_float4(0.f, 0.f, 0.f, 0.f);
        __syncthreads();
        Xs[lc+0][lr]=xv.x; Xs[lc+1][lr]=xv.y; Xs[lc+2][lr]=xv.z; Xs[lc+3][lr]=xv.w;
        Ws[lc+0][lr]=wv.x; Ws[lc+1][lr]=wv.y; Ws[lc+2][lr]=wv.z; Ws[lc+3][lr]=wv.w;
        __syncthreads();
        #pragma unroll
        for (int kk = 0; kk < 16; ++kk) {
            const float4 a = *(const float4*)(&Xs[kk][tm]);
            const float4 b = *(const float4*)(&Ws[kk][tn]);
            acc[0][0] += a.x*b.x; acc[0][1] += a.x*b.y; acc[0][2] += a.x*b.z; acc[0][3] += a.x*b.w;
            acc[1][0] += a.y*b.x; acc[1][1] += a.y*b.y; acc[1][2] += a.y*b.z; acc[1][3] += a.y*b.w;
            acc[2][0] += a.z*b.x; acc[2][1] += a.z*b.y; acc[2][2] += a.z*b.z; acc[2][3] += a.z*b.w;
            acc[3][0] += a.w*b.x; acc[3][1] += a.w*b.y; acc[3][2] += a.w*b.z; acc[3][3] += a.w*b.w;
        }
    }
    const int nc = n0 + tn;
    if (nc >= Nn) return;
    float4 bv = make_float4(0.f, 0.f, 0.f, 0.f);
    if (bias) bv = *(const float4*)(bias + nc);
    #pragma unroll
    for (int i = 0; i < 4; ++i) {
        float4 o;
        o.x = acc[i][0] + bv.x; o.y = acc[i][1] + bv.y;
        o.z = acc[i][2] + bv.z; o.w = acc[i][3] + bv.w;
        if (RELU) { o.x=fmaxf(o.x,0.f); o.y=fmaxf(o.y,0.f); o.z=fmaxf(o.z,0.f); o.w=fmaxf(o.w,0.f); }
        *(float4*)(Y + (size_t)(m0 + tm + i) * Nn + nc) = o;
    }
}

// ---------------------------------------------------------------------------
// Batched Y[b] = (A[b] @ H[b]) * mask[b,:,None], optional ReLU.
// ---------------------------------------------------------------------------
template<int RELU>
__global__ __launch_bounds__(256) void gemm_nn_mask(const float* __restrict__ A,
    const float* __restrict__ Hm, const float* __restrict__ mask,
    float* __restrict__ Y, int M, int K, int Nn)
{
    const int b = blockIdx.z;
    A  += (size_t)b * M * K;
    Hm += (size_t)b * K * Nn;
    Y  += (size_t)b * M * Nn;
    __shared__ float As[16][68];
    __shared__ float Hs[16][68];
    const int tid = threadIdx.x;
    const int m0 = blockIdx.y << 6;
    const int n0 = blockIdx.x << 6;
    const int lr = tid >> 2;
    const int lc = (tid & 3) << 2;
    const int hr = tid >> 4;           // 0..15
    const int hc = (tid & 15) << 2;    // 0..60
    const int tm = (tid >> 4) << 2;
    const int tn = (tid & 15) << 2;

    float acc[4][4] = {{0.f,0.f,0.f,0.f},{0.f,0.f,0.f,0.f},{0.f,0.f,0.f,0.f},{0.f,0.f,0.f,0.f}};

    for (int k0 = 0; k0 < K; k0 += 16) {
        float4 av = *(const float4*)(A + (size_t)(m0 + lr) * K + k0 + lc);
        float4 hv = *(const float4*)(Hm + (size_t)(k0 + hr) * Nn + n0 + hc);
        __syncthreads();
        As[lc+0][lr]=av.x; As[lc+1][lr]=av.y; As[lc+2][lr]=av.z; As[lc+3][lr]=av.w;
        *(float4*)(&Hs[hr][hc]) = hv;
        __syncthreads();
        #pragma unroll
        for (int kk = 0; kk < 16; ++kk) {
            const float4 a = *(const float4*)(&As[kk][tm]);
            const float4 h = *(const float4*)(&Hs[kk][tn]);
            acc[0][0] += a.x*h.x; acc[0][1] += a.x*h.y; acc[0][2] += a.x*h.z; acc[0][3] += a.x*h.w;
            acc[1][0] += a.y*h.x; acc[1][1] += a.y*h.y; acc[1][2] += a.y*h.z; acc[1][3] += a.y*h.w;
            acc[2][0] += a.z*h.x; acc[2][1] += a.z*h.y; acc[2][2] += a.z*h.z; acc[2][3] += a.z*h.w;
            acc[3][0] += a.w*h.x; acc[3][1] += a.w*h.y; acc[3][2] += a.w*h.z; acc[3][3] += a.w*h.w;
        }
    }
    #pragma unroll
    for (int i = 0; i < 4; ++i) {
        const float mk = mask[b * M + m0 + tm + i];
        float4 o;
        o.x = acc[i][0]*mk; o.y = acc[i][1]*mk; o.z = acc[i][2]*mk; o.w = acc[i][3]*mk;
        if (RELU) { o.x=fmaxf(o.x,0.f); o.y=fmaxf(o.y,0.f); o.z=fmaxf(o.z,0.f); o.w=fmaxf(o.w,0.f); }
        *(float4*)(Y + (size_t)(m0 + tm + i) * Nn + n0 + tn) = o;
    }
}

// ---------------------------------------------------------------------------
__global__ __launch_bounds__(256) void attn_sisj(const float* __restrict__ h,
    const float* __restrict__ aw, const float* __restrict__ ab,
    float* __restrict__ si, float* __restrict__ sj)
{
    const int lane = threadIdx.x & 63;
    const int row  = (blockIdx.x << 2) + (threadIdx.x >> 6);
    const float4 hv = ((const float4*)(h + (size_t)row * HDIM))[lane];
    const float4 a1 = ((const float4*)aw)[lane];
    const float4 a2 = ((const float4*)(aw + HDIM))[lane];
    float s1 = hv.x*a1.x + hv.y*a1.y + hv.z*a1.z + hv.w*a1.w;
    float s2 = hv.x*a2.x + hv.y*a2.y + hv.z*a2.z + hv.w*a2.w;
    #pragma unroll
    for (int off = 32; off > 0; off >>= 1) {
        s1 += __shfl_down(s1, off);
        s2 += __shfl_down(s2, off);
    }
    if (lane == 0) { si[row] = s1 + ab[0]; sj[row] = s2; }
}

// ---------------------------------------------------------------------------
__global__ __launch_bounds__(512) void attn_score(const float* __restrict__ si,
    const float* __restrict__ sj, const float* __restrict__ adj,
    const float* __restrict__ mask, float* __restrict__ watt)
{
    const int bi = blockIdx.x;           // b*NN + i
    const int b  = bi >> 9;
    const int j  = threadIdx.x;
    const float s0 = si[bi];
    const float mi = mask[bi];
    float s = sigmoidf_(s0 + sj[(b << 9) + j]) * adj[(size_t)bi * NN + j] * mi * mask[(b << 9) + j];
    float t = s;
    #pragma unroll
    for (int off = 32; off > 0; off >>= 1) t += __shfl_down(t, off);
    __shared__ float red[8];
    const int lane = j & 63, wv = j >> 6;
    if (lane == 0) red[wv] = t;
    __syncthreads();
    if (j == 0) {
        float tot = 0.f;
        #pragma unroll
        for (int w = 0; w < 8; ++w) tot += red[w];
        red[0] = 1.0f / (tot + 1e-8f);
    }
    __syncthreads();
    watt[(size_t)bi * NN + j] = s * red[0];
}

// ---------------------------------------------------------------------------
// Pack fp32 -> f16x2 (u32). n = element pairs.
// ---------------------------------------------------------------------------
__global__ __launch_bounds__(256) void pack_f16(const float* __restrict__ src,
    unsigned int* __restrict__ dst, int n)
{
    int i = blockIdx.x * 256 + threadIdx.x;
    if (i < n) {
        float2 v = ((const float2*)src)[i];
        _Float16 a = (_Float16)v.x, b = (_Float16)v.y;
        unsigned short ua = *(unsigned short*)&a, ub = *(unsigned short*)&b;
        dst[i] = (unsigned int)ua | ((unsigned int)ub << 16);
    }
}

// ---------------------------------------------------------------------------
// Single-block-per-chain LSTM scan, f16 weights CU-resident.
// Grid: 16 blocks (chain = batch*2+dir), 512 threads.
// amdgpu_waves_per_eu(2,2): dynamic LDS (135 KB) already limits the CU to one
// 8-wave block = 2 waves/SIMD, but the backend can't see extern-shared size,
// so without this attribute it targets >=4 waves/SIMD and caps VGPRs at 128,
// spilling the 192 pinned weight regs to scratch (round 6: VGPR=128, 2 us/step).
// With (2,2) the RA budget is 256 VGPRs: 48 uint4 weights stay resident.
// Thread t owns gate rows t and 512+t: u32[0..23] of each row's 32 uint4 in
// NAMED pinned registers, u32[24..31] in LDS (lane-contiguous, conflict-free).
// h is packed f16 in LDS (broadcast reads). 256 v_dot2_f32_f16/thread/step.
// Dynamic LDS: 16*512*16 (weights) + 1024*4 (g) + 128*4 (h2) = 135680 B.
// ---------------------------------------------------------------------------
__global__ __launch_bounds__(512) __attribute__((amdgpu_waves_per_eu(2, 2)))
void lstm_scan5(
    const float* __restrict__ pre_f, const float* __restrict__ pre_b,
    const unsigned int* __restrict__ w16_f, const unsigned int* __restrict__ w16_b,
    float* __restrict__ out)
{
    extern __shared__ unsigned int smem[];
    uint4v* lw4 = (uint4v*)smem;                   // [16][512] uint4
    float* g_s = (float*)(smem + 32768);           // [1024]
    unsigned int* h2 = smem + 32768 + 1024;        // [128] packed half2

    const int chain = blockIdx.x;
    const int batch = chain >> 1;
    const int dir   = chain & 1;
    const float* pre = dir ? pre_b : pre_f;
    const unsigned int* w = dir ? w16_b : w16_f;
    const int t0 = threadIdx.x;                    // 0..511

    const uint4v* wrA = (const uint4v*)(w + (size_t)t0 * 128);          // row t0
    const uint4v* wrB = (const uint4v*)(w + (size_t)(t0 + 512) * 128);  // row t0+512

#define WD(i) uint4v A##i = wrA[i]; uint4v B##i = wrB[i];
    WD(0) WD(1) WD(2) WD(3) WD(4) WD(5) WD(6) WD(7) WD(8) WD(9) WD(10) WD(11)
    WD(12) WD(13) WD(14) WD(15) WD(16) WD(17) WD(18) WD(19) WD(20) WD(21) WD(22) WD(23)
#undef WD
    // Pin: volatile asm results cannot be rematerialized -> weights stay in VGPRs.
#define PIN(x) asm volatile("" : "+v"(x));
    PIN(A0) PIN(A1) PIN(A2) PIN(A3) PIN(A4) PIN(A5) PIN(A6) PIN(A7) PIN(A8) PIN(A9)
    PIN(A10) PIN(A11) PIN(A12) PIN(A13) PIN(A14) PIN(A15) PIN(A16) PIN(A17) PIN(A18)
    PIN(A19) PIN(A20) PIN(A21) PIN(A22) PIN(A23)
    PIN(B0) PIN(B1) PIN(B2) PIN(B3) PIN(B4) PIN(B5) PIN(B6) PIN(B7) PIN(B8) PIN(B9)
    PIN(B10) PIN(B11) PIN(B12) PIN(B13) PIN(B14) PIN(B15) PIN(B16) PIN(B17) PIN(B18)
    PIN(B19) PIN(B20) PIN(B21) PIN(B22) PIN(B23)
#undef PIN

    // LDS tail: uint4 24..31 of each row, lane-contiguous layout.
    #pragma unroll
    for (int i = 0; i < 8; ++i) {
        lw4[i * 512 + t0]       = wrA[24 + i];
        lw4[(8 + i) * 512 + t0] = wrB[24 + i];
    }
    if (t0 < 128) h2[t0] = 0u;
    float c = 0.f;

    const int tt0 = dir ? (TT - 1) : 0;
    const long pstep = dir ? -1024 : 1024;
    const long ostep = dir ? -512 : 512;
    const float* ppA = pre + ((size_t)batch * TT + tt0) * 1024 + t0;
    const float* ppB = ppA + 512;
    float* op = out + ((size_t)batch * TT + tt0) * 512 + dir * 256 + t0;  // used by t0<256
    float pvA = *ppA; ppA += pstep;
    float pvB = *ppB; ppB += pstep;
    __syncthreads();

    for (int t = 0; t < TT; ++t) {
        // prefetch next step's pre values early (hidden under the dots)
        float pvA_n = 0.f, pvB_n = 0.f;
        if (t + 1 < TT) { pvA_n = *ppA; pvB_n = *ppB; }
        ppA += pstep; ppB += pstep;

        float a0 = 0.f, a1 = 0.f, a2 = 0.f, a3 = 0.f;
        float b0 = 0.f, b1 = 0.f, b2 = 0.f, b3 = 0.f;
        const uint4v* h4 = (const uint4v*)h2;
#define DOT2(i) { const uint4v hv = h4[i]; \
        a0 = fdot2_(A##i.x, hv.x, a0); a1 = fdot2_(A##i.y, hv.y, a1); \
        a2 = fdot2_(A##i.z, hv.z, a2); a3 = fdot2_(A##i.w, hv.w, a3); \
        b0 = fdot2_(B##i.x, hv.x, b0); b1 = fdot2_(B##i.y, hv.y, b1); \
        b2 = fdot2_(B##i.z, hv.z, b2); b3 = fdot2_(B##i.w, hv.w, b3); }
        DOT2(0) DOT2(1) DOT2(2) DOT2(3) DOT2(4) DOT2(5) DOT2(6) DOT2(7)
        DOT2(8) DOT2(9) DOT2(10) DOT2(11) DOT2(12) DOT2(13) DOT2(14) DOT2(15)
        DOT2(16) DOT2(17) DOT2(18) DOT2(19) DOT2(20) DOT2(21) DOT2(22) DOT2(23)
#undef DOT2
        #pragma unroll
        for (int i = 0; i < 8; ++i) {
            const uint4v wa = lw4[i * 512 + t0];
            const uint4v wb = lw4[(8 + i) * 512 + t0];
            const uint4v hv = h4[24 + i];
            a0 = fdot2_(wa.x, hv.x, a0); a1 = fdot2_(wa.y, hv.y, a1);
            a2 = fdot2_(wa.z, hv.z, a2); a3 = fdot2_(wa.w, hv.w, a3);
            b0 = fdot2_(wb.x, hv.x, b0); b1 = fdot2_(wb.y, hv.y, b1);
            b2 = fdot2_(wb.z, hv.z, b2); b3 = fdot2_(wb.w, hv.w, b3);
        }
        g_s[t0]       = (a0 + a1) + (a2 + a3) + pvA;
        g_s[512 + t0] = (b0 + b1) + (b2 + b3) + pvB;
        __syncthreads();
        if (t0 < 256) {
            const float ig = sigmoidf_(g_s[t0]);
            const float fg = sigmoidf_(g_s[256 + t0]);
            const float gg = tanhf_(g_s[512 + t0]);
            const float og = sigmoidf_(g_s[768 + t0]);
            c = fg * c + ig * gg;
            const float h = og * tanhf_(c);
            *op = h;
            op += ostep;
            _Float16 hh = (_Float16)h;
            ((unsigned short*)h2)[t0] = *(unsigned short*)&hh;
        }
        pvA = pvA_n; pvB = pvB_n;
        __syncthreads();
    }
}

// ---------------------------------------------------------------------------

extern "C" void kernel_launch(void* const* d_in, const int* in_sizes, int n_in,
                              void* d_out, int out_size, void* d_ws, size_t ws_size,
                              hipStream_t stream)
{
    const float* nf   = (const float*)d_in[0];
    const float* adj  = (const float*)d_in[1];
    const float* mask = (const float*)d_in[2];
    const float* g_w[3]  = {(const float*)d_in[4],  (const float*)d_in[8],  (const float*)d_in[12]};
    const float* g_b[3]  = {(const float*)d_in[5],  (const float*)d_in[9],  (const float*)d_in[13]};
    const float* g_aw[3] = {(const float*)d_in[6],  (const float*)d_in[10], (const float*)d_in[14]};
    const float* g_ab[3] = {(const float*)d_in[7],  (const float*)d_in[11], (const float*)d_in[15]};
    const float* wih0f = (const float*)d_in[16]; const float* whh0f = (const float*)d_in[17]; const float* b0f = (const float*)d_in[18];
    const float* wih0b = (const float*)d_in[19]; const float* whh0b = (const float*)d_in[20]; const float* b0b = (const float*)d_in[21];
    const float* wih1f = (const float*)d_in[22]; const float* whh1f = (const float*)d_in[23]; const float* b1f = (const float*)d_in[24];
    const float* wih1b = (const float*)d_in[25]; const float* whh1b = (const float*)d_in[26]; const float* b1b = (const float*)d_in[27];

    float* ws = (float*)d_ws;
    // Workspace layout (floats); total ~15.7M floats = ~63 MB
    float* bufA = ws;                       // (4096,256)  GNN h projection / head tmp
    float* bufB = bufA + 1048576;           // (4096,256)  GNN layer output; later f16 weights
    float* bufC = bufB + 1048576;           // (4096,256)  GNN3 output (kept for nd head)
    float* si   = bufC + 1048576;           // (4096)
    float* sj   = si + 4096;                // (4096)
    float* out0 = sj + 4096;                // (4096,512) LSTM layer0 output
    float* out1 = out0 + 2097152;           // (4096,512) LSTM layer1 output
    float* P0   = out1 + 2097152;           // (4096,1024) pre-activations fwd
    float* P1   = P0 + 4194304;             // (4096,1024) pre-activations bwd
    float* watt = P0;                       // alias: attention weights (GNN phase only)
    // packed f16 whh weights, aliased onto bufB (dead after GNN3):
    unsigned int* w16_0f = (unsigned int*)bufB;
    unsigned int* w16_0b = w16_0f + 131072;
    unsigned int* w16_1f = w16_0b + 131072;
    unsigned int* w16_1b = w16_1f + 131072;

    const int MR = BB * NN;                 // 4096 rows
    dim3 blk(256);
    const int SCAN_LDS = (32768 + 1024 + 128) * 4;   // 135680 B

    // ---------------- GNN x3 ----------------
    auto run_gnn = [&](const float* xin, int Kin, int li, float* ob, bool relu) {
        gemm_nt<0><<<dim3(HDIM / 64, MR / 64), blk, 0, stream>>>(xin, g_w[li], g_b[li], bufA, MR, Kin, HDIM);
        attn_sisj<<<dim3(MR / 4), blk, 0, stream>>>(bufA, g_aw[li], g_ab[li], si, sj);
        attn_score<<<dim3(MR), dim3(512), 0, stream>>>(si, sj, adj, mask, watt);
        if (relu)
            gemm_nn_mask<1><<<dim3(HDIM / 64, NN / 64, BB), blk, 0, stream>>>(watt, bufA, mask, ob, NN, NN, HDIM);
        else
            gemm_nn_mask<0><<<dim3(HDIM / 64, NN / 64, BB), blk, 0, stream>>>(watt, bufA, mask, ob, NN, NN, HDIM);
    };
    run_gnn(nf,   NDIM, 0, bufB, true);
    run_gnn(bufB, HDIM, 1, bufB, true);
    run_gnn(bufB, HDIM, 2, bufC, false);

    // ---------------- pack whh weights to f16 (bufB now dead) ----------------
    pack_f16<<<dim3(512), blk, 0, stream>>>(whh0f, w16_0f, 131072);
    pack_f16<<<dim3(512), blk, 0, stream>>>(whh0b, w16_0b, 131072);
    pack_f16<<<dim3(512), blk, 0, stream>>>(whh1f, w16_1f, 131072);
    pack_f16<<<dim3(512), blk, 0, stream>>>(whh1b, w16_1b, 131072);

    // ---------------- LSTM layer 0 ----------------
    gemm_nt<0><<<dim3(16, MR / 64), blk, 0, stream>>>(bufC, wih0f, b0f, P0, MR, HDIM, 1024);
    gemm_nt<0><<<dim3(16, MR / 64), blk, 0, stream>>>(bufC, wih0b, b0b, P1, MR, HDIM, 1024);
    lstm_scan5<<<dim3(16), dim3(512), SCAN_LDS, stream>>>(P0, P1, w16_0f, w16_0b, out0);

    // ---------------- LSTM layer 1 ----------------
    gemm_nt<0><<<dim3(16, MR / 64), blk, 0, stream>>>(out0, wih1f, b1f, P0, MR, 512, 1024);
    gemm_nt<0><<<dim3(16, MR / 64), blk, 0, stream>>>(out0, wih1b, b1b, P1, MR, 512, 1024);
    lstm_scan5<<<dim3(16), dim3(512), SCAN_LDS, stream>>>(P0, P1, w16_1f, w16_1b, out1);

    // ---------------- Heads ----------------
    float* out = (float*)d_out;
    // op: (B,N,64) at offset 0
    gemm_nt<1><<<dim3(4, MR / 64), blk, 0, stream>>>(out1, (const float*)d_in[28], (const float*)d_in[29], bufA, MR, 512, 256);
    gemm_nt<0><<<dim3(1, MR / 64), blk, 0, stream>>>(bufA, (const float*)d_in[30], (const float*)d_in[31], out, MR, 256, 64);
    // pp: (B,N,16) at offset 262144
    gemm_nt<1><<<dim3(4, MR / 64), blk, 0, stream>>>(out1, (const float*)d_in[32], (const float*)d_in[33], bufA, MR, 512, 256);
    gemm_nt<0><<<dim3(1, MR / 64), blk, 0, stream>>>(bufA, (const float*)d_in[34], (const float*)d_in[35], out + 262144, MR, 256, 16);
    // sk: (B,N,128) at offset 327680
    gemm_nt<1><<<dim3(4, MR / 64), blk, 0, stream>>>(out1, (const float*)d_in[36], (const float*)d_in[37], bufA, MR, 512, 256);
    gemm_nt<0><<<dim3(2, MR / 64), blk, 0, stream>>>(bufA, (const float*)d_in[38], (const float*)d_in[39], out + 327680, MR, 256, 128);
    // nd: (B,N,128) at offset 851968 (input = GNN3 output)
    gemm_nt<1><<<dim3(4, MR / 64), blk, 0, stream>>>(bufC, (const float*)d_in[40], (const float*)d_in[41], bufA, MR, 256, 256);
    gemm_nt<0><<<dim3(2, MR / 64), blk, 0, stream>>>(bufA, (const float*)d_in[42], (const float*)d_in[43], out + 851968, MR, 256, 128);
}